// Round 1
// baseline (1489.092 us; speedup 1.0000x reference)
//
#include <hip/hip_runtime.h>

#define TSTEPS 251
#define BT 16          // time-tile width (columns per tile)
#define BST (BT + 1)   // padded LDS row stride -> conflict-free (gcd(17,32)=1)
#define BLOCK 128      // threads per block = rows per block

// LDS: 6 input tiles + 1 output tile, each BLOCK x BST floats
// 7 * 128 * 17 * 4 = 60,928 B  -> 2 blocks/CU by LDS
__global__ __launch_bounds__(BLOCK) void gad_paths_kernel(
    const float* __restrict__ Z,
    const float* __restrict__ ua0,
    const float* __restrict__ ua1,
    const float* __restrict__ ub0,
    const float* __restrict__ ub1,
    const float* __restrict__ ug,
    float* __restrict__ out)
{
    __shared__ float lds[7][BLOCK * BST];
    const int tid  = threadIdx.x;
    const int row0 = blockIdx.x * BLOCK;

    const float dt   = 0.004f;
    const float sqdt = sqrtf(0.004f);   // constant-folded, IEEE f32 like jnp.sqrt
    float s = 100.0f;                   // S0

    for (int c0 = 0; c0 < TSTEPS; c0 += BT) {
        const int len = (TSTEPS - c0) < BT ? (TSTEPS - c0) : BT;

        // ---- cooperative coalesced load: 6 arrays, BLOCK x len tile ----
        {
            const float* __restrict__ srcs[6] = {Z, ua0, ua1, ub0, ub1, ug};
            #pragma unroll
            for (int a = 0; a < 6; ++a) {
                const float* __restrict__ src = srcs[a];
                #pragma unroll
                for (int k = 0; k < BT; ++k) {
                    int p = tid + k * BLOCK;     // linear tile index
                    int r = p >> 4;              // p / BT  (row within block)
                    int c = p & (BT - 1);        // p % BT  (col within tile)
                    float v = 0.0f;
                    if (c < len)
                        v = src[(long long)(row0 + r) * TSTEPS + (c0 + c)];
                    lds[a][r * BST + c] = v;
                }
            }
        }
        __syncthreads();

        // ---- per-row sequential recurrence over this tile ----
        {
            const int b = tid * BST;
            for (int j = 0; j < len; ++j) {
                if (c0 + j != 0) {   // col 0 is the initial condition S0
                    float z  = lds[0][b + j] * sqdt;
                    float a0 = 0.05f + (0.15f - 0.05f) * lds[1][b + j];
                    float a1 = 0.10f + (0.30f - 0.10f) * lds[2][b + j];
                    float b0 = (0.05f - 0.00f) * lds[3][b + j];
                    float b1 = (0.10f - 0.00f) * lds[4][b + j];
                    float g  = 0.80f + (1.00f - 0.80f) * lds[5][b + j];
                    float base = a0 + a1 * fmaxf(s, 0.0f);
                    s = s + (b0 + b1 * s) * dt + __powf(base, g) * z;
                }
                lds[6][b + j] = s;
            }
        }
        __syncthreads();

        // ---- cooperative coalesced store of the output tile ----
        #pragma unroll
        for (int k = 0; k < BT; ++k) {
            int p = tid + k * BLOCK;
            int r = p >> 4;
            int c = p & (BT - 1);
            if (c < len)
                out[(long long)(row0 + r) * TSTEPS + (c0 + c)] = lds[6][r * BST + c];
        }
        // next iteration's post-load __syncthreads() protects lds[6] reuse
    }
}

extern "C" void kernel_launch(void* const* d_in, const int* in_sizes, int n_in,
                              void* d_out, int out_size, void* d_ws, size_t ws_size,
                              hipStream_t stream)
{
    const float* Z   = (const float*)d_in[0];
    const float* ua0 = (const float*)d_in[1];
    const float* ua1 = (const float*)d_in[2];
    const float* ub0 = (const float*)d_in[3];
    const float* ub1 = (const float*)d_in[4];
    const float* ug  = (const float*)d_in[5];
    float* out = (float*)d_out;

    const int n_rows = in_sizes[0] / TSTEPS;   // 131072
    dim3 grid(n_rows / BLOCK), block(BLOCK);
    gad_paths_kernel<<<grid, block, 0, stream>>>(Z, ua0, ua1, ub0, ub1, ug, out);
}